// Round 11
// baseline (106.709 us; speedup 1.0000x reference)
//
#include <hip/hip_runtime.h>
#include <math.h>

// ---------------------------------------------------------------------------
// Problem: B=64 batches. a_p = a@W1^T + b1 [64,1024]; b_p = b@W2^T + b2.
// cost[b,i,j] = (a_p[b,i]-b_p[b,j])^2 ; DTW DP R[i,j]=cost+min(diag,up,left);
// out[b] = R[1023,1023].
// ---------------------------------------------------------------------------

#define L 1024
#define BATCH 64

// ---------------- GEMM: out[b,i] = sum_k X[b,k]*W[i,k] (+ bias) ------------
__global__ __launch_bounds__(256) void proj_kernel(
    const float* __restrict__ a, const float* __restrict__ b,
    const float* __restrict__ W1, const float* __restrict__ b1,
    const float* __restrict__ W2, const float* __restrict__ b2,
    float* __restrict__ ap, float* __restrict__ bp, int KC) {
  int part = blockIdx.x >> 7;
  int sub = blockIdx.x & 127;
  const float* X;
  const float* W;
  const float* bias;
  float* out;
  int i0;
  if (sub < 64) {
    X = a; W = W1; bias = b1; out = ap + part * BATCH * L; i0 = sub * 16;
  } else {
    X = b; W = W2; bias = b2; out = bp + part * BATCH * L; i0 = (sub - 64) * 16;
  }

  __shared__ float a_s[64][33];
  __shared__ float w_s[16][33];

  int tid = threadIdx.x;
  int lane_b = tid & 63;
  int iq = tid >> 6;

  float acc[4] = {0.f, 0.f, 0.f, 0.f};

  int kbeg = part * KC;
  int kend = kbeg + KC;
  for (int k0 = kbeg; k0 < kend; k0 += 32) {
    {
      int row = tid >> 2;
      int kl = (tid & 3) * 8;
      const float4* src = reinterpret_cast<const float4*>(&X[row * L + k0 + kl]);
      float4 v0 = src[0];
      float4 v1 = src[1];
      a_s[row][kl + 0] = v0.x; a_s[row][kl + 1] = v0.y;
      a_s[row][kl + 2] = v0.z; a_s[row][kl + 3] = v0.w;
      a_s[row][kl + 4] = v1.x; a_s[row][kl + 5] = v1.y;
      a_s[row][kl + 6] = v1.z; a_s[row][kl + 7] = v1.w;
    }
    {
      int row = tid >> 4;
      int kl = (tid & 15) * 2;
      float2 v = *reinterpret_cast<const float2*>(&W[(i0 + row) * L + k0 + kl]);
      w_s[row][kl] = v.x;
      w_s[row][kl + 1] = v.y;
    }
    __syncthreads();
    #pragma unroll 8
    for (int kl = 0; kl < 32; ++kl) {
      float av = a_s[lane_b][kl];
      #pragma unroll
      for (int m = 0; m < 4; ++m) {
        acc[m] += av * w_s[iq * 4 + m][kl];
      }
    }
    __syncthreads();
  }

  #pragma unroll
  for (int m = 0; m < 4; ++m) {
    int i = i0 + iq * 4 + m;
    float bv = (part == 0) ? bias[i] : 0.f;
    out[lane_b * L + i] = acc[m] + bv;
  }
}

// ---------------- DTW: 4 waves/batch, 2 ROWS per systolic step -------------
// Lane (w,t) owns CPL=4 columns from (w*64+t)*4; delay D = w*OFF + t STEPS.
// At step s the lane processes the row PAIR R0 = 2*(s-D), R1 = R0+1 for its
// 4 columns (a 2x4 tile). Boundary transport per step: the pair of
// right-edge values (e0,e1) moves lane t-1 -> t via two DPP wave_shr:1 with
// the ring feed in the `old` operand (lane 0); feeds walk down via shl1.
// Tile math (cost c[r][m] = (ap[Rr]-bp[col m])^2):
//   row0: x0_m = c0m + min3(p_m, diag, left)   diag = p_{m-1} | prev_l1
//                                              left = x0_{m-1} | l0
//   row1: x1_m = c1m + min3(x0_m, x0_{m-1}|l0, x1_{m-1}|l1)
//   new p_m = x1_m ; e0 = x0_3 ; e1 = x1_3 ; prev_l1 = l1.
// R[0,0]'s diag seed 0 comes via prev_l1 init (no left=0 seed, no fixup).
// Ring: float2 per producing step; EXACT R10 slot formulas in step units
// (GAP = OFF-63 = 32 = KBAR; producer of consumer-step s is step s-32).
// NSTEPS = 512 + DMAX = 864 (was 1376): ~1.6x fewer steps, chain grows only
// 8 -> ~12 ops (row chains overlap).

#define NW 4
#define CPL 4
#define KBAR 32
#define OFF 95                        // lane-delay skew; GAP = OFF-63 = 32
#define DMAXS (OFF * (NW - 1) + 63)   // 348 steps
#define NG 27                         // ceil((512 + DMAXS) / KBAR)
#define NSTEPS (NG * KBAR)            // 864
#define ROWPAD (2 * DMAXS)            // 696 (row-index offset, even)
#define APPAD (ROWPAD + 2 * NSTEPS + 8)  // 2432 floats

__device__ __forceinline__ float dpp_shr1(float v, float old) {
  // wave_shr:1, bound_ctrl=0: lane i <- lane i-1; lane 0 <- old[lane 0].
  int r = __builtin_amdgcn_update_dpp(__float_as_int(old), __float_as_int(v),
                                      0x138, 0xf, 0xf, false);
  return __int_as_float(r);
}

__device__ __forceinline__ float dpp_shl1(float v) {
  // wave_shl:1: lane i <- lane i+1; lane 63 keeps its value.
  int r = __builtin_amdgcn_update_dpp(__float_as_int(v), __float_as_int(v),
                                      0x130, 0xf, 0xf, false);
  return __int_as_float(r);
}

__device__ __forceinline__ float min3f(float x, float y, float z) {
  float r;
  asm("v_min3_f32 %0, %1, %2, %3" : "=v"(r) : "v"(x), "v"(y), "v"(z));
  return r;
}

__global__ __launch_bounds__(256, 1) void dtw_kernel(
    const float* __restrict__ app, const float* __restrict__ bpp,
    float* __restrict__ out, int parts) {
  const int b = blockIdx.x;
  const int tid = threadIdx.x;
  const int w = tid >> 6;
  const int t = tid & 63;
  const int woff = w * OFF;     // delay in steps
  const int D = woff + t;       // my delay in steps
  const float INF = INFINITY;

  __shared__ float ap_pad[APPAD];
  __shared__ float2 ring2[NW - 1][64];

  // ap_pad[ROWPAD + i] = sum_p ap_part[p][b,i]; zero skirts.
  for (int idx = tid; idx < APPAD; idx += 256) {
    int src = idx - ROWPAD;
    float v = 0.f;
    if ((unsigned)src < (unsigned)L) {
      v = app[b * L + src];
      for (int p = 1; p < parts; ++p) v += app[p * BATCH * L + b * L + src];
    }
    ap_pad[idx] = v;
  }

  float4 bv = *reinterpret_cast<const float4*>(&bpp[b * L + tid * CPL]);
  for (int p = 1; p < parts; ++p) {
    float4 u = *reinterpret_cast<const float4*>(
        &bpp[p * BATCH * L + b * L + tid * CPL]);
    bv.x += u.x; bv.y += u.y; bv.z += u.z; bv.w += u.w;
  }
  const float bpv0 = bv.x, bpv1 = bv.y, bpv2 = bv.z, bpv3 = bv.w;

  float p0 = INF, p1 = INF, p2 = INF, p3 = INF;  // prev row (R0-1) cells
  float e0 = INF, e1 = INF;      // my right-edge pair from last step
  float prev_l1 = (w == 0 && t == 0) ? 0.f : INF;  // diag seed for R[0,0]
  float rc0 = INF, rc1 = INF;    // ring feed pair (walks toward lane 0)
  float vp0 = INF, vp1 = INF;    // producer capture walkers

  // Per-lane pair pointer: apl2[s] = rows {2(s-D), 2(s-D)+1} (0 in skirts).
  const float2* apl2 =
      reinterpret_cast<const float2*>(ap_pad + (ROWPAD - 2 * D));

  __syncthreads();

  // One 32-step group. PRED: pair-validity predicate (ramp/drain phases).
#define DTW_GROUP(s0v, PRED)                                                 \
  {                                                                          \
    const int s0 = (s0v);                                                    \
    float2 apf[KBAR];                                                        \
    _Pragma("unroll")                                                        \
    for (int k = 0; k < KBAR; ++k) apf[k] = apl2[s0 + k];                    \
    if (w > 0 && t < KBAR) {                                                 \
      float2 rr = ring2[w - 1][(s0 - woff + t) & 63];                        \
      rc0 = rr.x; rc1 = rr.y;                                                \
    }                                                                        \
    _Pragma("unroll")                                                        \
    for (int k = 0; k < KBAR; ++k) {                                         \
      float l0 = dpp_shr1(e0, rc0);                                          \
      float l1 = dpp_shr1(e1, rc1);                                          \
      rc0 = dpp_shl1(rc0);                                                   \
      rc1 = dpp_shl1(rc1);                                                   \
      int ii = s0 + k - D;                                                   \
      if (!(PRED) || ((unsigned)ii < 512u)) {                                \
        float a0 = apf[k].x, a1 = apf[k].y;                                  \
        float d00 = a0 - bpv0, d01 = a0 - bpv1;                              \
        float d02 = a0 - bpv2, d03 = a0 - bpv3;                              \
        float d10 = a1 - bpv0, d11 = a1 - bpv1;                              \
        float d12 = a1 - bpv2, d13 = a1 - bpv3;                              \
        float x00 = __builtin_fmaf(d00, d00, min3f(p0, prev_l1, l0));        \
        float x01 = __builtin_fmaf(d01, d01, min3f(p1, p0, x00));            \
        float x02 = __builtin_fmaf(d02, d02, min3f(p2, p1, x01));            \
        float x03 = __builtin_fmaf(d03, d03, min3f(p3, p2, x02));            \
        float x10 = __builtin_fmaf(d10, d10, min3f(x00, l0, l1));            \
        float x11 = __builtin_fmaf(d11, d11, min3f(x01, x00, x10));          \
        float x12 = __builtin_fmaf(d12, d12, min3f(x02, x01, x11));          \
        float x13 = __builtin_fmaf(d13, d13, min3f(x03, x02, x12));          \
        p0 = x10; p1 = x11; p2 = x12; p3 = x13;                              \
        prev_l1 = l1;                                                        \
        e0 = x03; e1 = x13;                                                  \
      }                                                                      \
      vp0 = dpp_shl1(vp0);                                                   \
      vp0 = (t == 63) ? e0 : vp0;                                            \
      vp1 = dpp_shl1(vp1);                                                   \
      vp1 = (t == 63) ? e1 : vp1;                                            \
    }                                                                        \
    if (w < NW - 1 && t >= 64 - KBAR) {                                      \
      float2 st; st.x = vp0; st.y = vp1;                                     \
      ring2[w][(s0 + t - woff - (63 + KBAR)) & 63] = st;                     \
    }                                                                        \
    __syncthreads();                                                         \
  }

  // Ramp: groups 0..10 (steps 0..351 cover s < DMAXS=348, predicated).
  for (int g = 0; g < 11; ++g) DTW_GROUP(g * KBAR, true);
  // Steady: groups 11..15 (steps 352..511; all lanes' pairs in range).
  for (int g = 11; g < 16; ++g) DTW_GROUP(g * KBAR, false);
  // Drain: groups 16..26 (steps 512..863; last active step 859).
  for (int g = 16; g < NG; ++g) DTW_GROUP(g * KBAR, true);
#undef DTW_GROUP

  if (tid == NW * 64 - 1) out[b] = p3;  // R[1023,1023]
}

extern "C" void kernel_launch(void* const* d_in, const int* in_sizes, int n_in,
                              void* d_out, int out_size, void* d_ws, size_t ws_size,
                              hipStream_t stream) {
  const float* a  = (const float*)d_in[0];
  const float* b  = (const float*)d_in[1];
  const float* W1 = (const float*)d_in[2];
  const float* b1 = (const float*)d_in[3];
  const float* W2 = (const float*)d_in[4];
  const float* b2 = (const float*)d_in[5];
  float* out = (float*)d_out;

  size_t per_part = (size_t)2 * BATCH * L * sizeof(float);
  int parts = 1;
  if (ws_size >= 4 * per_part) parts = 4;
  else if (ws_size >= 2 * per_part) parts = 2;

  float* ap = (float*)d_ws;                    // parts x [BATCH, L]
  float* bp = ap + (size_t)parts * BATCH * L;  // parts x [BATCH, L]

  proj_kernel<<<128 * parts, 256, 0, stream>>>(a, b, W1, b1, W2, b2,
                                               ap, bp, L / parts);
  dtw_kernel<<<BATCH, 256, 0, stream>>>(ap, bp, out, parts);
}